// Round 1
// baseline (1473.500 us; speedup 1.0000x reference)
//
#include <hip/hip_runtime.h>
#include <hip/hip_bf16.h>
#include <stdint.h>

typedef unsigned short u16;
typedef unsigned int u32;

#define F1 274625   // 65^3
#define IJ1 4225    // 65^2

typedef float v4f __attribute__((ext_vector_type(4)));
typedef __bf16 v8bf __attribute__((ext_vector_type(8)));

__device__ __forceinline__ float lof(u32 u) { union { u32 u; float f; } c; c.u = u << 16; return c.f; }
__device__ __forceinline__ float hif(u32 u) { union { u32 u; float f; } c; c.u = u & 0xffff0000u; return c.f; }
__device__ __forceinline__ u16 f2bf(float f) {
  union { float f; u32 u; } c; c.f = f;
  u32 r = (c.u >> 16) & 1u;
  return (u16)((c.u + 0x7fffu + r) >> 16);
}
// pack two f32 (as bit patterns) -> two bf16 in one u32 (element a = low half)
__device__ __forceinline__ u32 pkbf(u32 a, u32 b) {
  union { float f; u32 u; } ca, cb; ca.u = a; cb.u = b;
  __hip_bfloat162 h = __float22bfloat162_rn(make_float2(ca.f, cb.f));
  union { __hip_bfloat162 h; u32 u; } c; c.h = h; return c.u;
}

// ---------------- K0: transpose vec1/2/3 [512][64] f32 -> xT [3][64][512] f32
__global__ void __launch_bounds__(256) k0_transpose(const float* __restrict__ v1,
    const float* __restrict__ v2, const float* __restrict__ v3, float* __restrict__ xT) {
  int g = blockIdx.x * 256 + threadIdx.x;
  if (g >= 3 * 64 * 512) return;
  int t = g >> 15, r = g & 32767;
  int d = r >> 9, b = r & 511;
  const float* v = (t == 0) ? v1 : ((t == 1) ? v2 : v3);
  xT[g] = v[b * 64 + d];
}

// ---------------- K1: bilinear partial sums -> zsum [3][64][512] f32 (atomic)
__global__ void __launch_bounds__(256) k1_bilinear(
    const float* __restrict__ zw1, const float* __restrict__ zw2, const float* __restrict__ zw3,
    const float* __restrict__ xT, float* __restrict__ zsum) {
  int bid = blockIdx.x;                 // 768 = t*256 + o*4 + bh*2 + ih
  int ih = bid & 1, bh = (bid >> 1) & 1;
  int o = (bid >> 2) & 63, t = bid >> 8;
  int b = bh * 256 + threadIdx.x;
  const float* zw = (t == 0) ? zw1 : ((t == 1) ? zw2 : zw3);
  const float* xiT = xT + ((t == 1) ? 32768 : 0);  // branches 0,2 use vec1; 1 uses vec2
  const float* x3T = xT + 65536;                   // j-side is always vec3
  float x3r[64];
#pragma unroll
  for (int j = 0; j < 64; ++j) x3r[j] = x3T[j * 512 + b];
  const float4* w4 = (const float4*)(zw + o * 4096);
  float acc = 0.f;
  int i0 = ih * 32;
#pragma unroll 2
  for (int i = i0; i < i0 + 32; ++i) {
    float xi = xiT[i * 512 + b];
    float s = 0.f;
#pragma unroll
    for (int q = 0; q < 16; ++q) {
      float4 w = w4[i * 16 + q];   // uniform index -> scalar loads
      s += w.x * x3r[q*4+0] + w.y * x3r[q*4+1] + w.z * x3r[q*4+2] + w.w * x3r[q*4+3];
    }
    acc += xi * s;
  }
  atomicAdd(&zsum[t * 32768 + o * 512 + b], acc);
}

// ---------------- K2: per-branch h/o layers -> oT f32 [3][65][512], o3row bf16 [512][72]
__global__ void __launch_bounds__(256) k2_branch(
    const float* __restrict__ hw1, const float* __restrict__ hb1,
    const float* __restrict__ ow1, const float* __restrict__ ob1,
    const float* __restrict__ hw2, const float* __restrict__ hb2,
    const float* __restrict__ ow2, const float* __restrict__ ob2,
    const float* __restrict__ hw3, const float* __restrict__ hb3,
    const float* __restrict__ ow3, const float* __restrict__ ob3,
    const float* __restrict__ zb1, const float* __restrict__ zb2, const float* __restrict__ zb3,
    const float* __restrict__ xT, const float* __restrict__ zsum,
    float* __restrict__ oT, u16* __restrict__ o3row) {
  int t = blockIdx.x >> 3, bc = blockIdx.x & 7;   // 24 blocks
  int lane = threadIdx.x & 63;
  int w = __builtin_amdgcn_readfirstlane((int)(threadIdx.x >> 6));
  int b = bc * 64 + lane;
  const float* hw = (t==0)?hw1:((t==1)?hw2:hw3);
  const float* hb = (t==0)?hb1:((t==1)?hb2:hb3);
  const float* ow = (t==0)?ow1:((t==1)?ow2:ow3);
  const float* ob = (t==0)?ob1:((t==1)?ob2:ob3);
  const float* zb = (t==0)?zb1:((t==1)?zb2:zb3);
  const float* xtT = xT + t * 32768;
  const float4* hw4 = (const float4*)hw;
  const float4* ow4 = (const float4*)ow;
  __shared__ float gT[64][68];
  float xr[64];
#pragma unroll
  for (int k = 0; k < 64; ++k) xr[k] = xtT[k * 512 + b];
#pragma unroll
  for (int ii = 0; ii < 16; ii += 4) {
    float gv[4];
#pragma unroll
    for (int q = 0; q < 4; ++q) {
      int i = w * 16 + ii + q;
      float a = hb[i];
#pragma unroll
      for (int kq = 0; kq < 16; ++kq) {
        float4 h4 = hw4[i * 16 + kq];
        a += h4.x * xr[kq*4+0] + h4.y * xr[kq*4+1] + h4.z * xr[kq*4+2] + h4.w * xr[kq*4+3];
      }
      float hv = fmaxf(a, 0.f);
      float z = zsum[t * 32768 + i * 512 + b] + zb[i];
      float sg = 1.f / (1.f + __expf(-z));
      gv[q] = sg * hv;
    }
    *(float4*)&gT[lane][w * 16 + ii] = make_float4(gv[0], gv[1], gv[2], gv[3]);
  }
  __syncthreads();
  float gr[64];
#pragma unroll
  for (int k = 0; k < 64; k += 4) {
    float4 g4 = *(const float4*)&gT[lane][k];
    gr[k] = g4.x; gr[k+1] = g4.y; gr[k+2] = g4.z; gr[k+3] = g4.w;
  }
#pragma unroll
  for (int ii = 0; ii < 16; ++ii) {
    int oo = w * 16 + ii;
    float a = ob[oo];
#pragma unroll
    for (int kq = 0; kq < 16; ++kq) {
      float4 o4 = ow4[oo * 16 + kq];
      a += o4.x * gr[kq*4+0] + o4.y * gr[kq*4+1] + o4.z * gr[kq*4+2] + o4.w * gr[kq*4+3];
    }
    float ov = fmaxf(a, 0.f);
    oT[(t * 65 + oo) * 512 + b] = ov;
    if (t == 2) o3row[b * 72 + oo] = f2bf(ov);
  }
  if (w == 0) oT[(t * 65 + 64) * 512 + b] = 1.f;       // ones column
  if (t == 2 && w == 1) {
    uint4 ones = make_uint4(0x3F80u, 0u, 0u, 0u);      // bf16 1.0, then zero pad
    *(uint4*)&o3row[b * 72 + 64] = ones;
  }
}

// ---------------- K4: main GEMM: C[b,o] = sum_f o123[b,f]*W1[o,f]
// o12 fused (from oT, f32); split-K partials stored (no atomics) when mode=1.
// bid swizzle: the 4 mbase blocks sharing a W slice land on the SAME XCD
// (bid%8 = XCD heuristic) so W is HBM-fetched once and L2-served 4x.
__global__ void __launch_bounds__(256, 2) k4_gemm(
    const float* __restrict__ W, const u16* __restrict__ o3row,
    const float* __restrict__ oT, float* __restrict__ accum,
    float* __restrict__ pbuf, int mode) {
  __shared__ u16 o3r[128 * 72];
  __shared__ u16 Bs[128 * 72];
  __shared__ float o12sf[128];
  int bid = blockIdx.x;                 // 512
  int xcd = bid & 7, slot = bid >> 3;
  int mb = slot & 3, ph = slot >> 2;    // ph in [0,16)
  int pair = ph * 8 + xcd;              // [0,128): (sK, nb)
  int sK = pair >> 1, nb = pair & 1;
  int mbase = mb * 128, nbase = nb * 128;
  int ij0 = (sK * IJ1) >> 6, ij1 = ((sK + 1) * IJ1) >> 6;
  int tid = threadIdx.x;
  {  // persistent o3 rows: contiguous copy [128][72] bf16
    const uint4* src = (const uint4*)(o3row + mbase * 72);
    uint4* dst = (uint4*)o3r;
    for (int u = tid; u < (128 * 72) / 8; u += 256) dst[u] = src[u];
  }
  int lane = tid & 63;
  int wid = __builtin_amdgcn_readfirstlane(tid >> 6);
  int wm = wid >> 1, wn = wid & 1;
  int lrow = lane & 15, lkg = lane >> 4;
  int rr_ = tid >> 1, hh = tid & 1;
  long growBase = (long)(nbase + rr_) * F1;     // f32 element index of row start
  int aoff0 = (wm * 64 + lrow) * 72 + lkg * 8;
  int boff0 = (wn * 64 + lrow) * 72 + lkg * 8;
  v4f acc[16] = {};
  const uint4* Wq = (const uint4*)W;

  auto issueW = [&](int ij, uint4* q) {
    long g0 = growBase + (long)ij * 65;
    long u4d = (g0 >> 2) + (long)hh * 8;
#pragma unroll
    for (int r = 0; r < 9; ++r) q[r] = Wq[u4d + r];
  };
  auto issueO = [&](int ij, float& A, float& Bv) {
    if (tid < 128) {
      int i = ij / 65, j = ij - i * 65;
      A  = oT[i * 512 + mbase + tid];
      Bv = oT[(65 + j) * 512 + mbase + tid];
    }
  };

  uint4 cq[9]; float cA = 0.f, cB = 0.f;
  issueW(ij0, cq);
  issueO(ij0, cA, cB);
  __syncthreads();
  for (int ij = ij0; ij < ij1; ++ij) {
    bool more = (ij + 1 < ij1);
    uint4 nq[9]; float nA = 0.f, nB = 0.f;
    if (more) { issueW(ij + 1, nq); issueO(ij + 1, nA, nB); }
    {  // stage W rows [o, ij*65 .. +65): dword realign, cvt->bf16
      long g0 = growBase + (long)ij * 65;
      int s4 = (int)(g0 & 3);
      u32 L[36] = {cq[0].x,cq[0].y,cq[0].z,cq[0].w, cq[1].x,cq[1].y,cq[1].z,cq[1].w,
                   cq[2].x,cq[2].y,cq[2].z,cq[2].w, cq[3].x,cq[3].y,cq[3].z,cq[3].w,
                   cq[4].x,cq[4].y,cq[4].z,cq[4].w, cq[5].x,cq[5].y,cq[5].z,cq[5].w,
                   cq[6].x,cq[6].y,cq[6].z,cq[6].w, cq[7].x,cq[7].y,cq[7].z,cq[7].w,
                   cq[8].x,cq[8].y,cq[8].z,cq[8].w};
      u32 A_[34], Bv[33];
#pragma unroll
      for (int j = 0; j < 34; ++j) A_[j] = (s4 & 2) ? L[j + 2] : L[j];
#pragma unroll
      for (int j = 0; j < 33; ++j) Bv[j] = (s4 & 1) ? A_[j + 1] : A_[j];
      u32 Pk[16];
#pragma unroll
      for (int c = 0; c < 16; ++c) Pk[c] = pkbf(Bv[2 * c], Bv[2 * c + 1]);
      u16* bp = &Bs[rr_ * 72 + hh * 32];
      *(uint4*)(bp + 0)  = make_uint4(Pk[0],  Pk[1],  Pk[2],  Pk[3]);
      *(uint4*)(bp + 8)  = make_uint4(Pk[4],  Pk[5],  Pk[6],  Pk[7]);
      *(uint4*)(bp + 16) = make_uint4(Pk[8],  Pk[9],  Pk[10], Pk[11]);
      *(uint4*)(bp + 24) = make_uint4(Pk[12], Pk[13], Pk[14], Pk[15]);
      if (hh) Bs[rr_ * 72 + 64] = (u16)(pkbf(Bv[32], Bv[32]) & 0xffffu); // col 64
    }
    if (tid < 128) o12sf[tid] = cA * cB;
    __syncthreads();
    v4f P[16] = {};
#pragma unroll
    for (int kk = 0; kk < 64; kk += 32) {
      v8bf af[4], bfr[4];
#pragma unroll
      for (int t2 = 0; t2 < 4; ++t2) {
        af[t2]  = *(const v8bf*)&o3r[aoff0 + t2 * (16 * 72) + kk];
        bfr[t2] = *(const v8bf*)&Bs [boff0 + t2 * (16 * 72) + kk];
      }
#pragma unroll
      for (int t2 = 0; t2 < 4; ++t2)
#pragma unroll
        for (int u2 = 0; u2 < 4; ++u2)
          P[t2 * 4 + u2] = __builtin_amdgcn_mfma_f32_16x16x32_bf16(af[t2], bfr[u2], P[t2 * 4 + u2], 0, 0, 0);
    }
    float vv[4];
#pragma unroll
    for (int u2 = 0; u2 < 4; ++u2) vv[u2] = lof((u32)Bs[(wn * 64 + u2 * 16 + lrow) * 72 + 64]);
    float sv[4][4];
#pragma unroll
    for (int t2 = 0; t2 < 4; ++t2) {
      float4 sp = *(const float4*)&o12sf[wm * 64 + t2 * 16 + lkg * 4];
      sv[t2][0] = sp.x; sv[t2][1] = sp.y; sv[t2][2] = sp.z; sv[t2][3] = sp.w;
    }
#pragma unroll
    for (int t2 = 0; t2 < 4; ++t2)
#pragma unroll
      for (int u2 = 0; u2 < 4; ++u2)
#pragma unroll
        for (int e = 0; e < 4; ++e)
          acc[t2 * 4 + u2][e] += sv[t2][e] * (P[t2 * 4 + u2][e] + vv[u2]);
    __syncthreads();
    if (more) {
#pragma unroll
      for (int r = 0; r < 9; ++r) cq[r] = nq[r];
      cA = nA; cB = nB;
    }
  }
  if (mode) {
    float* dst = pbuf + ((long)sK << 17);
#pragma unroll
    for (int t2 = 0; t2 < 4; ++t2) {
      int gb0 = mbase + wm * 64 + t2 * 16 + lkg * 4;
#pragma unroll
      for (int u2 = 0; u2 < 4; ++u2) {
        int go = nbase + wn * 64 + u2 * 16 + lrow;
#pragma unroll
        for (int e = 0; e < 4; ++e)
          dst[(gb0 + e) * 256 + go] = acc[t2 * 4 + u2][e];
      }
    }
  } else {
#pragma unroll
    for (int t2 = 0; t2 < 4; ++t2) {
      int gb0 = mbase + wm * 64 + t2 * 16 + lkg * 4;
#pragma unroll
      for (int u2 = 0; u2 < 4; ++u2) {
        int go = nbase + wn * 64 + u2 * 16 + lrow;
#pragma unroll
        for (int e = 0; e < 4; ++e)
          atomicAdd(&accum[(gb0 + e) * 256 + go], acc[t2 * 4 + u2][e]);
      }
    }
  }
}

// ---------------- K4R: reduce split-K partials [64][512][256] -> accum [512][256]
__global__ void __launch_bounds__(256) k4_reduce(const float* __restrict__ P,
                                                 float* __restrict__ accum) {
  int g = blockIdx.x * 256 + threadIdx.x;       // float4 index, 32768 total
  const v4f* p4 = (const v4f*)P;
  v4f s = p4[g];
#pragma unroll 4
  for (int k = 1; k < 64; ++k) s += p4[(k << 15) + g];
  ((v4f*)accum)[g] = s;
}

// ---------------- K5: enc2 with relu(enc1)+skip concat -> out f32 [512][256]
__global__ void __launch_bounds__(256) k5_enc2(
    const float* __restrict__ accum, const float* __restrict__ oT,
    const float* __restrict__ enc1b, const float* __restrict__ w2,
    const float* __restrict__ enc2b, float* __restrict__ outp) {
  int bg = blockIdx.x >> 3, og = blockIdx.x & 7;   // 64 blocks
  int lane = threadIdx.x & 63;
  int w = __builtin_amdgcn_readfirstlane((int)(threadIdx.x >> 6));
  int b = bg * 64 + lane;
  int obase = og * 32 + w * 8;
  float a8[8];
#pragma unroll
  for (int q = 0; q < 8; ++q) a8[q] = enc2b[obase + q];
  for (int c = 0; c < 256; ++c) {
    float x = fmaxf(accum[b * 256 + c] + enc1b[c], 0.f);
#pragma unroll
    for (int q = 0; q < 8; ++q) a8[q] += w2[(obase + q) * 451 + c] * x;
  }
  for (int e = 0; e < 195; ++e) {
    float x = oT[e * 512 + b];   // rows: o1(65), o2(65), o3(65) — matches concat order
#pragma unroll
    for (int q = 0; q < 8; ++q) a8[q] += w2[(obase + q) * 451 + 256 + e] * x;
  }
#pragma unroll
  for (int q = 0; q < 8; ++q) outp[b * 256 + obase + q] = fmaxf(a8[q], 0.f);
}

extern "C" void kernel_launch(void* const* d_in, const int* in_sizes, int n_in,
                              void* d_out, int out_size, void* d_ws, size_t ws_size,
                              hipStream_t stream) {
  const float* vec1 = (const float*)d_in[0];
  const float* vec2 = (const float*)d_in[1];
  const float* vec3 = (const float*)d_in[2];
  const float* h1w = (const float*)d_in[3];  const float* h1b = (const float*)d_in[4];
  const float* z1w = (const float*)d_in[5];  const float* z1b = (const float*)d_in[6];
  const float* o1w = (const float*)d_in[7];  const float* o1b = (const float*)d_in[8];
  const float* h2w = (const float*)d_in[9];  const float* h2b = (const float*)d_in[10];
  const float* z2w = (const float*)d_in[11]; const float* z2b = (const float*)d_in[12];
  const float* o2w = (const float*)d_in[13]; const float* o2b = (const float*)d_in[14];
  const float* h3w = (const float*)d_in[15]; const float* h3b = (const float*)d_in[16];
  const float* z3w = (const float*)d_in[17]; const float* z3b = (const float*)d_in[18];
  const float* o3w = (const float*)d_in[19]; const float* o3b = (const float*)d_in[20];
  const float* e1w = (const float*)d_in[21]; const float* e1b = (const float*)d_in[22];
  const float* e2w = (const float*)d_in[23]; const float* e2b = (const float*)d_in[24];

  char* ws = (char*)d_ws;
  float* accum = (float*)(ws + 0);              // 512*256*4 = 524288
  float* oT    = (float*)(ws + 524288);         // 3*65*512*4 = 399360
  u16* o3row   = (u16*)  (ws + 923648);         // 512*72*2   = 73728
  float* xT    = (float*)(ws + 997376);         // 3*64*512*4 = 393216
  float* zsum  = (float*)(ws + 1390592);        // 3*64*512*4 = 393216
  float* pbuf  = (float*)(ws + 1783808);        // 64*512*256*4 = 33554432
  size_t need = 1783808 + (size_t)64 * 512 * 256 * 4;
  int mode = (ws_size >= need) ? 1 : 0;
  float* pArg = mode ? pbuf : accum;

  hipMemsetAsync(accum, 0, 524288, stream);
  hipMemsetAsync(zsum, 0, 393216, stream);

  hipLaunchKernelGGL(k0_transpose, dim3(384), dim3(256), 0, stream, vec1, vec2, vec3, xT);
  hipLaunchKernelGGL(k1_bilinear, dim3(768), dim3(256), 0, stream, z1w, z2w, z3w, xT, zsum);
  hipLaunchKernelGGL(k2_branch, dim3(24), dim3(256), 0, stream,
                     h1w, h1b, o1w, o1b, h2w, h2b, o2w, o2b, h3w, h3b, o3w, o3b,
                     z1b, z2b, z3b, xT, zsum, oT, o3row);
  hipLaunchKernelGGL(k4_gemm, dim3(512), dim3(256), 0, stream, e1w, o3row, oT, accum,
                     pArg, mode);
  if (mode)
    hipLaunchKernelGGL(k4_reduce, dim3(128), dim3(256), 0, stream, pbuf, accum);
  hipLaunchKernelGGL(k5_enc2, dim3(64), dim3(256), 0, stream, accum, oT, e1b, e2w, e2b,
                     (float*)d_out);
}

// Round 2
// 720.686 us; speedup vs baseline: 2.0446x; 2.0446x over previous
//
#include <hip/hip_runtime.h>
#include <hip/hip_bf16.h>
#include <stdint.h>

typedef unsigned short u16;
typedef unsigned int u32;

#define F1 274625   // 65^3
#define IJ1 4225    // 65^2

typedef float v4f __attribute__((ext_vector_type(4)));
typedef __bf16 v8bf __attribute__((ext_vector_type(8)));

__device__ __forceinline__ float lof(u32 u) { union { u32 u; float f; } c; c.u = u << 16; return c.f; }
__device__ __forceinline__ float hif(u32 u) { union { u32 u; float f; } c; c.u = u & 0xffff0000u; return c.f; }
__device__ __forceinline__ u16 f2bf(float f) {
  union { float f; u32 u; } c; c.f = f;
  u32 r = (c.u >> 16) & 1u;
  return (u16)((c.u + 0x7fffu + r) >> 16);
}
// pack two f32 (as bit patterns) -> two bf16 in one u32 (element a = low half)
__device__ __forceinline__ u32 pkbf(u32 a, u32 b) {
  union { float f; u32 u; } ca, cb; ca.u = a; cb.u = b;
  __hip_bfloat162 h = __float22bfloat162_rn(make_float2(ca.f, cb.f));
  union { __hip_bfloat162 h; u32 u; } c; c.h = h; return c.u;
}

// ---------------- K0: transpose vec1/2/3 [512][64] f32 -> xT [3][64][512] f32
__global__ void __launch_bounds__(256) k0_transpose(const float* __restrict__ v1,
    const float* __restrict__ v2, const float* __restrict__ v3, float* __restrict__ xT) {
  int g = blockIdx.x * 256 + threadIdx.x;
  if (g >= 3 * 64 * 512) return;
  int t = g >> 15, r = g & 32767;
  int d = r >> 9, b = r & 511;
  const float* v = (t == 0) ? v1 : ((t == 1) ? v2 : v3);
  xT[g] = v[b * 64 + d];
}

// ---------------- K1: bilinear partial sums -> zsum [3][64][512] f32 (atomic)
__global__ void __launch_bounds__(256) k1_bilinear(
    const float* __restrict__ zw1, const float* __restrict__ zw2, const float* __restrict__ zw3,
    const float* __restrict__ xT, float* __restrict__ zsum) {
  int bid = blockIdx.x;                 // 768 = t*256 + o*4 + bh*2 + ih
  int ih = bid & 1, bh = (bid >> 1) & 1;
  int o = (bid >> 2) & 63, t = bid >> 8;
  int b = bh * 256 + threadIdx.x;
  const float* zw = (t == 0) ? zw1 : ((t == 1) ? zw2 : zw3);
  const float* xiT = xT + ((t == 1) ? 32768 : 0);  // branches 0,2 use vec1; 1 uses vec2
  const float* x3T = xT + 65536;                   // j-side is always vec3
  float x3r[64];
#pragma unroll
  for (int j = 0; j < 64; ++j) x3r[j] = x3T[j * 512 + b];
  const float4* w4 = (const float4*)(zw + o * 4096);
  float acc = 0.f;
  int i0 = ih * 32;
#pragma unroll 2
  for (int i = i0; i < i0 + 32; ++i) {
    float xi = xiT[i * 512 + b];
    float s = 0.f;
#pragma unroll
    for (int q = 0; q < 16; ++q) {
      float4 w = w4[i * 16 + q];   // uniform index -> scalar loads
      s += w.x * x3r[q*4+0] + w.y * x3r[q*4+1] + w.z * x3r[q*4+2] + w.w * x3r[q*4+3];
    }
    acc += xi * s;
  }
  atomicAdd(&zsum[t * 32768 + o * 512 + b], acc);
}

// ---------------- K2: per-branch h/o layers -> oT f32 [3][65][512], o3row bf16 [512][72]
__global__ void __launch_bounds__(256) k2_branch(
    const float* __restrict__ hw1, const float* __restrict__ hb1,
    const float* __restrict__ ow1, const float* __restrict__ ob1,
    const float* __restrict__ hw2, const float* __restrict__ hb2,
    const float* __restrict__ ow2, const float* __restrict__ ob2,
    const float* __restrict__ hw3, const float* __restrict__ hb3,
    const float* __restrict__ ow3, const float* __restrict__ ob3,
    const float* __restrict__ zb1, const float* __restrict__ zb2, const float* __restrict__ zb3,
    const float* __restrict__ xT, const float* __restrict__ zsum,
    float* __restrict__ oT, u16* __restrict__ o3row) {
  int t = blockIdx.x >> 3, bc = blockIdx.x & 7;   // 24 blocks
  int lane = threadIdx.x & 63;
  int w = __builtin_amdgcn_readfirstlane((int)(threadIdx.x >> 6));
  int b = bc * 64 + lane;
  const float* hw = (t==0)?hw1:((t==1)?hw2:hw3);
  const float* hb = (t==0)?hb1:((t==1)?hb2:hb3);
  const float* ow = (t==0)?ow1:((t==1)?ow2:ow3);
  const float* ob = (t==0)?ob1:((t==1)?ob2:ob3);
  const float* zb = (t==0)?zb1:((t==1)?zb2:zb3);
  const float* xtT = xT + t * 32768;
  const float4* hw4 = (const float4*)hw;
  const float4* ow4 = (const float4*)ow;
  __shared__ float gT[64][68];
  float xr[64];
#pragma unroll
  for (int k = 0; k < 64; ++k) xr[k] = xtT[k * 512 + b];
#pragma unroll
  for (int ii = 0; ii < 16; ii += 4) {
    float gv[4];
#pragma unroll
    for (int q = 0; q < 4; ++q) {
      int i = w * 16 + ii + q;
      float a = hb[i];
#pragma unroll
      for (int kq = 0; kq < 16; ++kq) {
        float4 h4 = hw4[i * 16 + kq];
        a += h4.x * xr[kq*4+0] + h4.y * xr[kq*4+1] + h4.z * xr[kq*4+2] + h4.w * xr[kq*4+3];
      }
      float hv = fmaxf(a, 0.f);
      float z = zsum[t * 32768 + i * 512 + b] + zb[i];
      float sg = 1.f / (1.f + __expf(-z));
      gv[q] = sg * hv;
    }
    *(float4*)&gT[lane][w * 16 + ii] = make_float4(gv[0], gv[1], gv[2], gv[3]);
  }
  __syncthreads();
  float gr[64];
#pragma unroll
  for (int k = 0; k < 64; k += 4) {
    float4 g4 = *(const float4*)&gT[lane][k];
    gr[k] = g4.x; gr[k+1] = g4.y; gr[k+2] = g4.z; gr[k+3] = g4.w;
  }
#pragma unroll
  for (int ii = 0; ii < 16; ++ii) {
    int oo = w * 16 + ii;
    float a = ob[oo];
#pragma unroll
    for (int kq = 0; kq < 16; ++kq) {
      float4 o4 = ow4[oo * 16 + kq];
      a += o4.x * gr[kq*4+0] + o4.y * gr[kq*4+1] + o4.z * gr[kq*4+2] + o4.w * gr[kq*4+3];
    }
    float ov = fmaxf(a, 0.f);
    oT[(t * 65 + oo) * 512 + b] = ov;
    if (t == 2) o3row[b * 72 + oo] = f2bf(ov);
  }
  if (w == 0) oT[(t * 65 + 64) * 512 + b] = 1.f;       // ones column
  if (t == 2 && w == 1) {
    uint4 ones = make_uint4(0x3F80u, 0u, 0u, 0u);      // bf16 1.0, then zero pad
    *(uint4*)&o3row[b * 72 + 64] = ones;
  }
}

// pack one staged W row-half: 32 dwords (+col64 on hh=1), compile-time shift S4.
// Realign is pure register renaming; writes swizzled 16B chunks.
template<int S4>
__device__ __forceinline__ void pack_row(const uint4* qv, char* bsB, int sxor, int hh) {
  u32 l[36];
#pragma unroll
  for (int r = 0; r < 9; ++r) {
    l[4*r+0] = qv[r].x; l[4*r+1] = qv[r].y; l[4*r+2] = qv[r].z; l[4*r+3] = qv[r].w;
  }
#pragma unroll
  for (int m = 0; m < 4; ++m) {
    u32 p0 = pkbf(l[S4+8*m+0], l[S4+8*m+1]);
    u32 p1 = pkbf(l[S4+8*m+2], l[S4+8*m+3]);
    u32 p2 = pkbf(l[S4+8*m+4], l[S4+8*m+5]);
    u32 p3 = pkbf(l[S4+8*m+6], l[S4+8*m+7]);
    *(uint4*)(bsB + ((hh*64 + m*16) ^ sxor)) = make_uint4(p0, p1, p2, p3);
  }
  if (hh) *(u16*)(bsB + 128) = (u16)(pkbf(l[S4+32], l[S4+32]) & 0xffffu);  // col 64
}

// ---------------- K4: main GEMM: C[b,o] = sum_f o123[b,f]*W1[o,f]
// Row-rotated staging (wave-uniform alignment phase), XOR-swizzled LDS,
// P folded per-t2, 1-deep reg prefetch, split-K partials (mode=1) or atomics.
__global__ void __launch_bounds__(256, 2) k4_gemm(
    const float* __restrict__ W, const u16* __restrict__ o3row,
    const float* __restrict__ oT, float* __restrict__ accum,
    float* __restrict__ pbuf, int mode) {
  __shared__ u16 o3r[128 * 72];
  __shared__ u16 Bs[128 * 72];
  __shared__ float o12sf[128];
  int bid = blockIdx.x;                 // 512; same-XCD grouping of W-slice sharers
  int xcd = bid & 7, slot = bid >> 3;
  int mb = slot & 3, ph = slot >> 2;    // ph in [0,16)
  int pair = ph * 8 + xcd;              // [0,128): (sK, nb)
  int sK = pair >> 1, nb = pair & 1;
  int mbase = mb * 128, nbase = nb * 128;
  int ij0 = (sK * IJ1) >> 6, ij1 = ((sK + 1) * IJ1) >> 6;
  int tid = threadIdx.x;

  // persistent o3 rows -> LDS, swizzled 16B chunks (cols 64.. never read by MFMA)
  for (int u = tid; u < 1024; u += 256) {
    int r = u >> 3, c = u & 7;
    const uint4 v = *(const uint4*)(o3row + (mbase + r) * 72 + c * 8);
    *(uint4*)((char*)o3r + r * 144 + ((c * 16) ^ (((r >> 2) & 7) << 4))) = v;
  }

  int lane = tid & 63;
  int wid = __builtin_amdgcn_readfirstlane(tid >> 6);
  int wm = wid >> 1, wn = wid & 1;
  int lrow = lane & 15, lkg = lane >> 4;
  int rpos = lane >> 1, hh = lane & 1;   // 32 row-slots per wave, 2 threads/row

  // precomputed swizzled fragment byte-offsets
  int aoffB[4][2], boffB[4][2], vvoff[4];
#pragma unroll
  for (int u = 0; u < 4; ++u) {
    int ra = wm * 64 + u * 16 + lrow;
    int rb = wn * 64 + u * 16 + lrow;
#pragma unroll
    for (int k2 = 0; k2 < 2; ++k2) {
      aoffB[u][k2] = ra * 144 + ((lkg * 16 + k2 * 64) ^ (((ra >> 2) & 7) << 4));
      boffB[u][k2] = rb * 144 + ((lkg * 16 + k2 * 64) ^ (((rb >> 2) & 7) << 4));
    }
    vvoff[u] = rb * 72 + 64;
  }

  v4f acc[16] = {};
  const uint4* Wq = (const uint4*)W;
  uint4 qv[9];
  float cA = 0.f, cB = 0.f;
  {  // prologue loads for ij0
    int cc = (wid - ij0) & 3;
    int row = rpos * 4 + cc;
    long g = (long)(nbase + row) * F1 + (long)ij0 * 65;
    long u4 = (g >> 2) + (long)hh * 8;
#pragma unroll
    for (int r = 0; r < 9; ++r) qv[r] = Wq[u4 + r];
    int i = ij0 / 65, j = ij0 - i * 65;
    if (tid < 128) {
      cA = oT[i * 512 + mbase + tid];
      cB = oT[(65 + j) * 512 + mbase + tid];
    }
  }
  __syncthreads();

#pragma unroll 1
  for (int ij = ij0; ij < ij1; ++ij) {
    {  // stage: wave-uniform alignment phase S4 == wid (row rotation makes it so)
      int cc = (wid - ij) & 3;
      int row = rpos * 4 + cc;
      char* bsB = (char*)Bs + row * 144;
      int sxor = ((row >> 2) & 7) << 4;
      if      (wid == 0) pack_row<0>(qv, bsB, sxor, hh);
      else if (wid == 1) pack_row<1>(qv, bsB, sxor, hh);
      else if (wid == 2) pack_row<2>(qv, bsB, sxor, hh);
      else               pack_row<3>(qv, bsB, sxor, hh);
    }
    if (tid < 128) o12sf[tid] = cA * cB;
    if (ij + 1 < ij1) {  // reissue prefetch into the same regs (consumed above)
      int cc = (wid - (ij + 1)) & 3;
      int row = rpos * 4 + cc;
      long g = (long)(nbase + row) * F1 + (long)(ij + 1) * 65;
      long u4 = (g >> 2) + (long)hh * 8;
#pragma unroll
      for (int r = 0; r < 9; ++r) qv[r] = Wq[u4 + r];
      int i = (ij + 1) / 65, j = (ij + 1) - i * 65;
      if (tid < 128) {
        cA = oT[i * 512 + mbase + tid];
        cB = oT[(65 + j) * 512 + mbase + tid];
      }
    }
    __syncthreads();

    // B fragments resident (32 regs), A per-t2, P folded immediately (16 regs)
    v8bf bf0[2], bf1[2], bf2[2], bf3[2];
#pragma unroll
    for (int k2 = 0; k2 < 2; ++k2) {
      bf0[k2] = *(const v8bf*)((const char*)Bs + boffB[0][k2]);
      bf1[k2] = *(const v8bf*)((const char*)Bs + boffB[1][k2]);
      bf2[k2] = *(const v8bf*)((const char*)Bs + boffB[2][k2]);
      bf3[k2] = *(const v8bf*)((const char*)Bs + boffB[3][k2]);
    }
    float vv0 = lof((u32)Bs[vvoff[0]]);
    float vv1 = lof((u32)Bs[vvoff[1]]);
    float vv2 = lof((u32)Bs[vvoff[2]]);
    float vv3 = lof((u32)Bs[vvoff[3]]);
#pragma unroll
    for (int t2 = 0; t2 < 4; ++t2) {
      v8bf a0 = *(const v8bf*)((const char*)o3r + aoffB[t2][0]);
      v8bf a1 = *(const v8bf*)((const char*)o3r + aoffB[t2][1]);
      v4f P0 = {}, P1 = {}, P2 = {}, P3 = {};
      P0 = __builtin_amdgcn_mfma_f32_16x16x32_bf16(a0, bf0[0], P0, 0, 0, 0);
      P0 = __builtin_amdgcn_mfma_f32_16x16x32_bf16(a1, bf0[1], P0, 0, 0, 0);
      P1 = __builtin_amdgcn_mfma_f32_16x16x32_bf16(a0, bf1[0], P1, 0, 0, 0);
      P1 = __builtin_amdgcn_mfma_f32_16x16x32_bf16(a1, bf1[1], P1, 0, 0, 0);
      P2 = __builtin_amdgcn_mfma_f32_16x16x32_bf16(a0, bf2[0], P2, 0, 0, 0);
      P2 = __builtin_amdgcn_mfma_f32_16x16x32_bf16(a1, bf2[1], P2, 0, 0, 0);
      P3 = __builtin_amdgcn_mfma_f32_16x16x32_bf16(a0, bf3[0], P3, 0, 0, 0);
      P3 = __builtin_amdgcn_mfma_f32_16x16x32_bf16(a1, bf3[1], P3, 0, 0, 0);
      float4 sp = *(const float4*)&o12sf[wm * 64 + t2 * 16 + lkg * 4];
#pragma unroll
      for (int e = 0; e < 4; ++e) {
        float se = (e == 0) ? sp.x : (e == 1) ? sp.y : (e == 2) ? sp.z : sp.w;
        acc[t2 * 4 + 0][e] += se * (P0[e] + vv0);
        acc[t2 * 4 + 1][e] += se * (P1[e] + vv1);
        acc[t2 * 4 + 2][e] += se * (P2[e] + vv2);
        acc[t2 * 4 + 3][e] += se * (P3[e] + vv3);
      }
    }
    __syncthreads();
  }

  if (mode) {
    float* dst = pbuf + ((long)sK << 17);
#pragma unroll
    for (int t2 = 0; t2 < 4; ++t2) {
      int gb0 = mbase + wm * 64 + t2 * 16 + lkg * 4;
#pragma unroll
      for (int u2 = 0; u2 < 4; ++u2) {
        int go = nbase + wn * 64 + u2 * 16 + lrow;
#pragma unroll
        for (int e = 0; e < 4; ++e)
          dst[(gb0 + e) * 256 + go] = acc[t2 * 4 + u2][e];
      }
    }
  } else {
#pragma unroll
    for (int t2 = 0; t2 < 4; ++t2) {
      int gb0 = mbase + wm * 64 + t2 * 16 + lkg * 4;
#pragma unroll
      for (int u2 = 0; u2 < 4; ++u2) {
        int go = nbase + wn * 64 + u2 * 16 + lrow;
#pragma unroll
        for (int e = 0; e < 4; ++e)
          atomicAdd(&accum[(gb0 + e) * 256 + go], acc[t2 * 4 + u2][e]);
      }
    }
  }
}

// ---------------- K4R: reduce split-K partials [64][512][256] -> accum [512][256]
__global__ void __launch_bounds__(256) k4_reduce(const float* __restrict__ P,
                                                 float* __restrict__ accum) {
  int g = blockIdx.x * 256 + threadIdx.x;       // float4 index, 32768 total
  const v4f* p4 = (const v4f*)P;
  v4f s = p4[g];
#pragma unroll 4
  for (int k = 1; k < 64; ++k) s += p4[(k << 15) + g];
  ((v4f*)accum)[g] = s;
}

// ---------------- K5: enc2 with relu(enc1)+skip concat -> out f32 [512][256]
__global__ void __launch_bounds__(256) k5_enc2(
    const float* __restrict__ accum, const float* __restrict__ oT,
    const float* __restrict__ enc1b, const float* __restrict__ w2,
    const float* __restrict__ enc2b, float* __restrict__ outp) {
  int bg = blockIdx.x >> 3, og = blockIdx.x & 7;   // 64 blocks
  int lane = threadIdx.x & 63;
  int w = __builtin_amdgcn_readfirstlane((int)(threadIdx.x >> 6));
  int b = bg * 64 + lane;
  int obase = og * 32 + w * 8;
  float a8[8];
#pragma unroll
  for (int q = 0; q < 8; ++q) a8[q] = enc2b[obase + q];
  for (int c = 0; c < 256; ++c) {
    float x = fmaxf(accum[b * 256 + c] + enc1b[c], 0.f);
#pragma unroll
    for (int q = 0; q < 8; ++q) a8[q] += w2[(obase + q) * 451 + c] * x;
  }
  for (int e = 0; e < 195; ++e) {
    float x = oT[e * 512 + b];   // rows: o1(65), o2(65), o3(65) — matches concat order
#pragma unroll
    for (int q = 0; q < 8; ++q) a8[q] += w2[(obase + q) * 451 + 256 + e] * x;
  }
#pragma unroll
  for (int q = 0; q < 8; ++q) outp[b * 256 + obase + q] = fmaxf(a8[q], 0.f);
}

extern "C" void kernel_launch(void* const* d_in, const int* in_sizes, int n_in,
                              void* d_out, int out_size, void* d_ws, size_t ws_size,
                              hipStream_t stream) {
  const float* vec1 = (const float*)d_in[0];
  const float* vec2 = (const float*)d_in[1];
  const float* vec3 = (const float*)d_in[2];
  const float* h1w = (const float*)d_in[3];  const float* h1b = (const float*)d_in[4];
  const float* z1w = (const float*)d_in[5];  const float* z1b = (const float*)d_in[6];
  const float* o1w = (const float*)d_in[7];  const float* o1b = (const float*)d_in[8];
  const float* h2w = (const float*)d_in[9];  const float* h2b = (const float*)d_in[10];
  const float* z2w = (const float*)d_in[11]; const float* z2b = (const float*)d_in[12];
  const float* o2w = (const float*)d_in[13]; const float* o2b = (const float*)d_in[14];
  const float* h3w = (const float*)d_in[15]; const float* h3b = (const float*)d_in[16];
  const float* z3w = (const float*)d_in[17]; const float* z3b = (const float*)d_in[18];
  const float* o3w = (const float*)d_in[19]; const float* o3b = (const float*)d_in[20];
  const float* e1w = (const float*)d_in[21]; const float* e1b = (const float*)d_in[22];
  const float* e2w = (const float*)d_in[23]; const float* e2b = (const float*)d_in[24];

  char* ws = (char*)d_ws;
  float* accum = (float*)(ws + 0);              // 512*256*4 = 524288
  float* oT    = (float*)(ws + 524288);         // 3*65*512*4 = 399360
  u16* o3row   = (u16*)  (ws + 923648);         // 512*72*2   = 73728
  float* xT    = (float*)(ws + 997376);         // 3*64*512*4 = 393216
  float* zsum  = (float*)(ws + 1390592);        // 3*64*512*4 = 393216
  float* pbuf  = (float*)(ws + 1783808);        // 64*512*256*4 = 33554432
  size_t need = 1783808 + (size_t)64 * 512 * 256 * 4;
  int mode = (ws_size >= need) ? 1 : 0;
  float* pArg = mode ? pbuf : accum;

  hipMemsetAsync(accum, 0, 524288, stream);
  hipMemsetAsync(zsum, 0, 393216, stream);

  hipLaunchKernelGGL(k0_transpose, dim3(384), dim3(256), 0, stream, vec1, vec2, vec3, xT);
  hipLaunchKernelGGL(k1_bilinear, dim3(768), dim3(256), 0, stream, z1w, z2w, z3w, xT, zsum);
  hipLaunchKernelGGL(k2_branch, dim3(24), dim3(256), 0, stream,
                     h1w, h1b, o1w, o1b, h2w, h2b, o2w, o2b, h3w, h3b, o3w, o3b,
                     z1b, z2b, z3b, xT, zsum, oT, o3row);
  hipLaunchKernelGGL(k4_gemm, dim3(512), dim3(256), 0, stream, e1w, o3row, oT, accum,
                     pArg, mode);
  if (mode)
    hipLaunchKernelGGL(k4_reduce, dim3(128), dim3(256), 0, stream, pbuf, accum);
  hipLaunchKernelGGL(k5_enc2, dim3(64), dim3(256), 0, stream, accum, oT, e1b, e2w, e2b,
                     (float*)d_out);
}